// Round 11
// baseline (161.473 us; speedup 1.0000x reference)
//
#include <hip/hip_runtime.h>
#include <hip/hip_fp16.h>
#include <stdint.h>

#define CBP_D 8192
#define CBP_C 512
#define CBP_W 512
#define ROWS 64          // rows staged per block; lane covers 4 rows
#define NTHREADS 1024    // 16 waves
#define NSPLIT 4         // 64 row-blocks x 4 = 256 blocks = 1/CU
#define NCAP 72          // fixed pair-list capacity per d

// LDS layout (bytes): x2 rows 0..512 (513*128, row 512 = zeros), then x1 rows 0..511
#define X1OFF 65664
#define PADW  (512u << 17)   // pad pair word: j=512 (zero row), i=0

// ================= precompute (single fused kernel) =================
// 128 blocks x 512 threads. Each block independently rebuilds the h2 bucket
// tables in LDS (redundant, concurrent), then builds pair lists for its
// 64 d's with 8 threads per d. Deterministic: bucket order via rank, i-major.
__global__ __launch_bounds__(512, 2)
void pB_fill(const int* __restrict__ h1, const int* __restrict__ h2,
             int* __restrict__ cnt, uint32_t* __restrict__ pairs) {
    __shared__ int sc[CBP_D];       // 32 KB: h2 histogram (counts per bucket)
    __shared__ int sb[CBP_D];       // 32 KB: bucket start offsets
    __shared__ int ssum[512];
    __shared__ short sbk[CBP_C];    // bucket-ordered j list
    __shared__ int sh1[CBP_C];
    __shared__ int sh2[CBP_C];
    __shared__ int pc[64][8];       // per-(d, part) pair counts
    __shared__ int rawt[64];        // per-d totals
    int tid = threadIdx.x;          // 512

    for (int k = tid; k < CBP_D; k += 512) sc[k] = 0;
    sh1[tid] = h1[tid];
    sh2[tid] = h2[tid];
    __syncthreads();
    atomicAdd(&sc[sh2[tid]], 1);    // LDS histogram; counts order-independent
    __syncthreads();
    // exclusive scan of sc -> sb (512 threads x 16 bins)
    int base = tid * 16;
    int loc[16]; int s = 0;
#pragma unroll
    for (int k = 0; k < 16; ++k) { loc[k] = sc[base + k]; s += loc[k]; }
    ssum[tid] = s;
    __syncthreads();
    int acc = s;
    for (int off = 1; off < 512; off <<= 1) {
        int add = (tid >= off) ? ssum[tid - off] : 0;
        __syncthreads();
        acc += add; ssum[tid] = acc;
        __syncthreads();
    }
    int excl = acc - s;
#pragma unroll
    for (int k = 0; k < 16; ++k) { sb[base + k] = excl; excl += loc[k]; }
    __syncthreads();
    // deterministic bucket fill: rank of j among equal h2 values
    {
        int h = sh2[tid]; int r = 0;
        for (int j2 = 0; j2 < tid; ++j2) r += (sh2[j2] == h);
        sbk[sb[h] + r] = (short)tid;
    }
    __syncthreads();

    // ---- pair-list build: 8 threads per d, 64 d's per block ----
    int dl = tid >> 3, p = tid & 7;
    int d = blockIdx.x * 64 + dl;
    int i0 = p << 6;                 // 64 i's per part
    int cp = 0;
#pragma unroll 4
    for (int i = i0; i < i0 + 64; ++i) cp += sc[(d - sh1[i]) & (CBP_D - 1)];
    pc[dl][p] = cp;
    __syncthreads();
    int off = 0, tot = 0;
#pragma unroll
    for (int p2 = 0; p2 < 8; ++p2) { int v = pc[dl][p2]; off += (p2 < p) ? v : 0; tot += v; }
    uint32_t* pd = pairs + (size_t)d * NCAP;
    int pos = off;
    for (int i = i0; i < i0 + 64; ++i) {
        int t = (d - sh1[i]) & (CBP_D - 1);
        int n = sc[t];
        if (n) {
            int bo = sb[t];
            uint32_t iw = (uint32_t)(i << 7);
            for (int k = 0; k < n; ++k)
                pd[pos++] = iw | ((uint32_t)sbk[bo + k] << 17);
        }
    }
    if (p == 0) rawt[dl] = tot;
    __syncthreads();
    int q = dl & ~3;
    int qmax = max(max(rawt[q], rawt[q + 1]), max(rawt[q + 2], rawt[q + 3]));
    qmax = (qmax + 3) & ~3;
    for (int pos2 = tot + p; pos2 < qmax; pos2 += 8) pd[pos2] = PADW;
    if (p == 0) cnt[d] = qmax;
}

// ================= main =================

// Quarter g (lane>>4) owns d = quadbase+g; lane l (lane&15) covers rows 4l..4l+3.
#define PROC(P) { \
    uint32_t p_ = (P); \
    uint32_t aB_ = (p_ & 0x1FF80u) + baseA; \
    uint32_t bB_ = ((p_ >> 10) & 0x1FF80u) | baseB; \
    uint2 ra_ = *(const uint2*)(xsh + aB_); \
    uint2 rb_ = *(const uint2*)(xsh + bB_); \
    a01 = __hfma2(*(const __half2*)&ra_.x, *(const __half2*)&rb_.x, a01); \
    a23 = __hfma2(*(const __half2*)&ra_.y, *(const __half2*)&rb_.y, a23); }

// Process one quad (4 consecutive d); result float4 (this lane's row, 4 d) in DEST.
// Pipeline: 3 uint4s in flight within the quad (cur/nx1/nx2); 2 uint4s + count
// preloaded across the quad boundary (pp0_cur/pp1_cur/nmax_cur).
#define QUAD(K, DEST) { \
    int q_ = (qq << 2) + (K); \
    int quadbase_ = dbase + (q_ << 2); \
    int nmax_ = nmax_cur; \
    int nb_ = nmax_ >> 2; \
    const uint4* pl4_ = (const uint4*)(pairs + (size_t)(quadbase_ + g4) * NCAP); \
    int nq_ = (q_ + 1 < 32) ? q_ + 1 : 31; \
    const uint4* pl4n_ = (const uint4*)(pairs + (size_t)(dbase + (nq_ << 2) + g4) * NCAP); \
    int nmax_n_ = __builtin_amdgcn_readfirstlane(cnt[dbase + (nq_ << 2)]); \
    uint4 cur_ = pp0_cur; \
    uint4 nx1_ = pp1_cur; \
    uint4 nx2_ = pl4_[(2 < nb_) ? 2 : (nb_ > 0 ? nb_ - 1 : 0)]; \
    uint4 pp0n_ = pl4n_[0]; \
    uint4 pp1n_ = pl4n_[1]; \
    float ac0 = 0.f, ac1 = 0.f, ac2 = 0.f, ac3 = 0.f; \
    int t4_ = 0; \
    while (t4_ < nb_) { \
        __half2 a01 = __floats2half2_rn(0.f, 0.f); \
        __half2 a23 = __floats2half2_rn(0.f, 0.f); \
        int ce_ = (t4_ + 4 < nb_) ? t4_ + 4 : nb_; \
        for (; t4_ < ce_; ++t4_) { \
            uint4 c_ = cur_; \
            cur_ = nx1_; nx1_ = nx2_; \
            int nxt2_ = (t4_ + 3 < nb_) ? t4_ + 3 : nb_ - 1; \
            nx2_ = pl4_[nxt2_]; \
            PROC(c_.x); PROC(c_.y); PROC(c_.z); PROC(c_.w); \
        } \
        float2 u_ = __half22float2(a01); ac0 += u_.x; ac1 += u_.y; \
        float2 v_ = __half22float2(a23); ac2 += v_.x; ac3 += v_.y; \
    } \
    nmax_cur = nmax_n_; pp0_cur = pp0n_; pp1_cur = pp1n_; \
    float s0_ = __shfl_xor(ac0, 16, 64), s1_ = __shfl_xor(ac1, 16, 64); \
    float s2_ = __shfl_xor(ac2, 16, 64), s3_ = __shfl_xor(ac3, 16, 64); \
    bool ge1_ = (g4 & 1) == 0; \
    float n0_ = ge1_ ? ac0 : s1_, n1_ = ge1_ ? s0_ : ac1; \
    float n2_ = ge1_ ? ac2 : s3_, n3_ = ge1_ ? s2_ : ac3; \
    s0_ = __shfl_xor(n0_, 32, 64); s1_ = __shfl_xor(n1_, 32, 64); \
    s2_ = __shfl_xor(n2_, 32, 64); s3_ = __shfl_xor(n3_, 32, 64); \
    bool ge2_ = (g4 & 2) == 0; \
    DEST = make_float4(ge2_ ? n0_ : s2_, ge2_ ? n1_ : s3_, \
                       ge2_ ? s0_ : n2_, ge2_ ? s1_ : n3_); }

__global__ __launch_bounds__(NTHREADS, 4)
void k_main(const float* __restrict__ b1, const float* __restrict__ b2,
            const float* __restrict__ s1, const float* __restrict__ s2,
            const int* __restrict__ cnt, const uint32_t* __restrict__ pairs,
            float* __restrict__ out) {
    __shared__ __align__(16) char xsh[131200];   // x2 (513 rows incl zero) + x1 (512)
    int bx = blockIdx.x;                   // 0..63 row-block
    int gy = blockIdx.y;                   // 0..3
    int r_base = bx * ROWS;
    int b = r_base >> 9;
    int w0 = r_base & (CBP_W - 1);
    int tid = threadIdx.x;

    // stage sign-folded f16, transposed [c][r]; x2 at 0, x1 at X1OFF
    for (int u = tid; u < CBP_C * 8; u += NTHREADS) {
        int c = u >> 3;
        int r8 = (u & 7) << 3;
        size_t g = ((size_t)(b * CBP_C + c)) * CBP_W + w0 + r8;
        float4 u0 = *(const float4*)(b1 + g), u1 = *(const float4*)(b1 + g + 4);
        float4 v0 = *(const float4*)(b2 + g), v1 = *(const float4*)(b2 + g + 4);
        float sa = s1[c], sb = s2[c];
        union { __half2 h2[4]; uint4 q; } A, Bv;
        A.h2[0] = __floats2half2_rn(u0.x * sa, u0.y * sa);
        A.h2[1] = __floats2half2_rn(u0.z * sa, u0.w * sa);
        A.h2[2] = __floats2half2_rn(u1.x * sa, u1.y * sa);
        A.h2[3] = __floats2half2_rn(u1.z * sa, u1.w * sa);
        Bv.h2[0] = __floats2half2_rn(v0.x * sb, v0.y * sb);
        Bv.h2[1] = __floats2half2_rn(v0.z * sb, v0.w * sb);
        Bv.h2[2] = __floats2half2_rn(v1.x * sb, v1.y * sb);
        Bv.h2[3] = __floats2half2_rn(v1.z * sb, v1.w * sb);
        *(uint4*)(xsh + X1OFF + (c << 7) + (r8 << 1)) = A.q;
        *(uint4*)(xsh + (c << 7) + (r8 << 1)) = Bv.q;
    }
    if (tid < 8) *(uint4*)(xsh + 65536 + tid * 16) = make_uint4(0, 0, 0, 0);
    __syncthreads();

    int wv = tid >> 6;                     // 0..15
    int lane = tid & 63;
    int g4 = lane >> 4;                    // quarter: d within quad
    int l = lane & 15;                     // rows 4l..4l+3
    uint32_t baseA = (uint32_t)(X1OFF + (l << 3));
    uint32_t baseB = (uint32_t)(l << 3);
    int dbase = gy * (CBP_D / NSPLIT) + wv * 128;   // wave owns 128 contiguous d's

    // cross-quad pipeline: count + first TWO uint4s of the upcoming quad
    int nmax_cur = __builtin_amdgcn_readfirstlane(cnt[dbase]);
    const uint4* pl40 = (const uint4*)(pairs + (size_t)(dbase + g4) * NCAP);
    uint4 pp0_cur = pl40[0];
    uint4 pp1_cur = pl40[1];

    // lane stores row r_base + 4l + g4, 16 consecutive d (64 B) per burst
    float* obase = out + (size_t)(r_base + (l << 2) + g4) * CBP_D + dbase;

    for (int qq = 0; qq < 8; ++qq) {
        float4 B0, B1, B2, B3;
        QUAD(0, B0); QUAD(1, B1); QUAD(2, B2); QUAD(3, B3);
        float* o_ = obase + (qq << 4);
        *(float4*)(o_)      = B0;
        *(float4*)(o_ + 4)  = B1;
        *(float4*)(o_ + 8)  = B2;
        *(float4*)(o_ + 12) = B3;
    }
}

// ================= launch =================

extern "C" void kernel_launch(void* const* d_in, const int* in_sizes, int n_in,
                              void* d_out, int out_size, void* d_ws, size_t ws_size,
                              hipStream_t stream) {
    const float* b1 = (const float*)d_in[0];
    const float* b2 = (const float*)d_in[1];
    const int*   h1 = (const int*)d_in[2];
    const float* s1 = (const float*)d_in[3];
    const int*   h2 = (const int*)d_in[4];
    const float* s2 = (const float*)d_in[5];
    float* out = (float*)d_out;

    int* cnt = (int*)d_ws;                            // 8192 (+8 pad)
    uint32_t* pairs = (uint32_t*)(cnt + 8192 + 8);    // 8192*NCAP u32 + slack (~2.36 MB)

    pB_fill<<<128, 512, 0, stream>>>(h1, h2, cnt, pairs);

    dim3 g(CBP_W * 8 / ROWS, NSPLIT);     // (64, 4)
    k_main<<<g, NTHREADS, 0, stream>>>(b1, b2, s1, s2, cnt, pairs, out);
}

// Round 12
// 156.379 us; speedup vs baseline: 1.0326x; 1.0326x over previous
//
#include <hip/hip_runtime.h>
#include <hip/hip_fp16.h>
#include <stdint.h>

#define CBP_D 8192
#define CBP_C 512
#define CBP_W 512
#define ROWS 32          // rows staged per block; lane covers 4 rows; 8 lanes/group
#define NTHREADS 1024    // 16 waves
#define NSPLIT 4         // 128 row-blocks x 4 = 512 blocks = 2/CU
#define NCAP 72          // fixed pair-list capacity per d

// LDS layout (bytes): x2 channels 0..512 at stride 72 (ch 512 = zeros), then x1.
// Pair words carry i*9 / j*9 so byte offset = (field)<<3.
#define X1OFF 36936      // 513*72
#define ZOFF  36864      // zero channel (j=512) byte offset: 512*72
#define PADW  ((uint32_t)4608u << 16)   // pad word: j*9=4608 (zero ch), i=0
#define LDSSZ 73800      // X1OFF + 512*72

// ================= precompute (single fused kernel) =================
// 128 blocks x 512 threads; block rebuilds h2 buckets in LDS, then builds
// pair lists for its 64 d's with 8 threads per d. OCTET-max padded (8
// consecutive d share a uniform count). Deterministic ordering throughout.
__global__ __launch_bounds__(512, 2)
void pB_fill(const int* __restrict__ h1, const int* __restrict__ h2,
             int* __restrict__ cnt, uint32_t* __restrict__ pairs) {
    __shared__ int sc[CBP_D];       // h2 histogram
    __shared__ int sb[CBP_D];       // bucket start offsets
    __shared__ int ssum[512];
    __shared__ short sbk[CBP_C];    // bucket-ordered j list
    __shared__ int sh1[CBP_C];
    __shared__ int sh2[CBP_C];
    __shared__ int pc[64][8];
    __shared__ int rawt[64];
    int tid = threadIdx.x;          // 512

    for (int k = tid; k < CBP_D; k += 512) sc[k] = 0;
    sh1[tid] = h1[tid];
    sh2[tid] = h2[tid];
    __syncthreads();
    atomicAdd(&sc[sh2[tid]], 1);
    __syncthreads();
    int base = tid * 16;
    int loc[16]; int s = 0;
#pragma unroll
    for (int k = 0; k < 16; ++k) { loc[k] = sc[base + k]; s += loc[k]; }
    ssum[tid] = s;
    __syncthreads();
    int acc = s;
    for (int off = 1; off < 512; off <<= 1) {
        int add = (tid >= off) ? ssum[tid - off] : 0;
        __syncthreads();
        acc += add; ssum[tid] = acc;
        __syncthreads();
    }
    int excl = acc - s;
#pragma unroll
    for (int k = 0; k < 16; ++k) { sb[base + k] = excl; excl += loc[k]; }
    __syncthreads();
    {
        int h = sh2[tid]; int r = 0;
        for (int j2 = 0; j2 < tid; ++j2) r += (sh2[j2] == h);
        sbk[sb[h] + r] = (short)tid;
    }
    __syncthreads();

    // ---- pair-list build: 8 threads per d, 64 d's per block ----
    int dl = tid >> 3, p = tid & 7;
    int d = blockIdx.x * 64 + dl;
    int i0 = p << 6;
    int cp = 0;
#pragma unroll 4
    for (int i = i0; i < i0 + 64; ++i) cp += sc[(d - sh1[i]) & (CBP_D - 1)];
    pc[dl][p] = cp;
    __syncthreads();
    int off = 0, tot = 0;
#pragma unroll
    for (int p2 = 0; p2 < 8; ++p2) { int v = pc[dl][p2]; off += (p2 < p) ? v : 0; tot += v; }
    uint32_t* pd = pairs + (size_t)d * NCAP;
    int pos = off;
    for (int i = i0; i < i0 + 64; ++i) {
        int t = (d - sh1[i]) & (CBP_D - 1);
        int n = sc[t];
        if (n) {
            int bo = sb[t];
            uint32_t iw = (uint32_t)(i * 9);
            for (int k = 0; k < n; ++k)
                pd[pos++] = iw | ((uint32_t)((int)sbk[bo + k] * 9) << 16);
        }
    }
    if (p == 0) rawt[dl] = tot;
    __syncthreads();
    int q = dl & ~7;                // octet of 8 consecutive d
    int omax = 0;
#pragma unroll
    for (int z = 0; z < 8; ++z) omax = max(omax, rawt[q + z]);
    omax = (omax + 3) & ~3;
    for (int pos2 = tot + p; pos2 < omax; pos2 += 8) pd[pos2] = PADW;
    if (p == 0) cnt[d] = omax;
}

// ================= main =================

// Group grp (lane>>3) owns d = octbase+grp; lane l (lane&7) covers rows 4l..4l+3.
#define PROC(P) { \
    uint32_t p_ = (P); \
    uint32_t aB_ = ((p_ & 0xFFFFu) << 3) + baseA; \
    uint32_t bB_ = ((p_ >> 16) << 3) + baseB; \
    uint2 ra_ = *(const uint2*)(xsh + aB_); \
    uint2 rb_ = *(const uint2*)(xsh + bB_); \
    a01 = __hfma2(*(const __half2*)&ra_.x, *(const __half2*)&rb_.x, a01); \
    a23 = __hfma2(*(const __half2*)&ra_.y, *(const __half2*)&rb_.y, a23); }

// One octet (8 consecutive d). DEST = this lane's (row rr, d octbase+dq*4..+3).
// Cross-octet pipeline: nmax_cur / pp_cur hold next octet's count + first uint4.
#define OCT(K, DEST) { \
    int oc_ = (oo << 1) + (K); \
    int octb_ = dbase + (oc_ << 3); \
    int nmax_ = nmax_cur; \
    uint4 cur_ = pp_cur; \
    int no_ = (oc_ + 1 < 16) ? oc_ + 1 : 15; \
    int nmax_n_ = __builtin_amdgcn_readfirstlane(cnt[dbase + (no_ << 3)]); \
    uint4 pp_n_ = *(const uint4*)(pairs + (size_t)(dbase + (no_ << 3) + grp) * NCAP); \
    const uint4* pl4_ = (const uint4*)(pairs + (size_t)(octb_ + grp) * NCAP); \
    float ac0 = 0.f, ac1 = 0.f, ac2 = 0.f, ac3 = 0.f; \
    int nb_ = nmax_ >> 2; \
    int t4_ = 0; \
    while (t4_ < nb_) { \
        __half2 a01 = __floats2half2_rn(0.f, 0.f); \
        __half2 a23 = __floats2half2_rn(0.f, 0.f); \
        int ce_ = (t4_ + 4 < nb_) ? t4_ + 4 : nb_; \
        for (; t4_ < ce_; ++t4_) { \
            uint4 c_ = cur_; \
            int nxt_ = (t4_ + 1 < nb_) ? t4_ + 1 : t4_; \
            cur_ = pl4_[nxt_]; \
            PROC(c_.x); PROC(c_.y); PROC(c_.z); PROC(c_.w); \
        } \
        float2 u_ = __half22float2(a01); ac0 += u_.x; ac1 += u_.y; \
        float2 v_ = __half22float2(a23); ac2 += v_.x; ac3 += v_.y; \
    } \
    nmax_cur = nmax_n_; pp_cur = pp_n_; \
    float v0_, v1_, v2_, v3_; \
    { float u0_ = __shfl(ac0, srcb, 64), u1_ = __shfl(ac1, srcb, 64); \
      float u2_ = __shfl(ac2, srcb, 64), u3_ = __shfl(ac3, srcb, 64); \
      v0_ = kk == 0 ? u0_ : kk == 1 ? u1_ : kk == 2 ? u2_ : u3_; } \
    { float u0_ = __shfl(ac0, srcb + 8, 64), u1_ = __shfl(ac1, srcb + 8, 64); \
      float u2_ = __shfl(ac2, srcb + 8, 64), u3_ = __shfl(ac3, srcb + 8, 64); \
      v1_ = kk == 0 ? u0_ : kk == 1 ? u1_ : kk == 2 ? u2_ : u3_; } \
    { float u0_ = __shfl(ac0, srcb + 16, 64), u1_ = __shfl(ac1, srcb + 16, 64); \
      float u2_ = __shfl(ac2, srcb + 16, 64), u3_ = __shfl(ac3, srcb + 16, 64); \
      v2_ = kk == 0 ? u0_ : kk == 1 ? u1_ : kk == 2 ? u2_ : u3_; } \
    { float u0_ = __shfl(ac0, srcb + 24, 64), u1_ = __shfl(ac1, srcb + 24, 64); \
      float u2_ = __shfl(ac2, srcb + 24, 64), u3_ = __shfl(ac3, srcb + 24, 64); \
      v3_ = kk == 0 ? u0_ : kk == 1 ? u1_ : kk == 2 ? u2_ : u3_; } \
    DEST = make_float4(v0_, v1_, v2_, v3_); }

__global__ __launch_bounds__(NTHREADS, 8)
void k_main(const float* __restrict__ b1, const float* __restrict__ b2,
            const float* __restrict__ s1, const float* __restrict__ s2,
            const int* __restrict__ cnt, const uint32_t* __restrict__ pairs,
            float* __restrict__ out) {
    __shared__ __align__(16) char xsh[LDSSZ];   // x2 (513 ch @72B incl zero) + x1 (512 ch)
    int bx = blockIdx.x;                   // 0..127 row-block (32 rows)
    int gy = blockIdx.y;                   // 0..3
    int r_base = bx * ROWS;
    int b = r_base >> 9;
    int w0 = r_base & (CBP_W - 1);
    int tid = threadIdx.x;

    // stage sign-folded f16 transposed [c][r] at 72 B channel stride
    for (int u = tid; u < CBP_C * 4; u += NTHREADS) {   // 2048 units: (c, 8 rows)
        int c = u >> 2;
        int r8 = (u & 3) << 3;
        size_t g = ((size_t)(b * CBP_C + c)) * CBP_W + w0 + r8;
        float4 u0 = *(const float4*)(b1 + g), u1 = *(const float4*)(b1 + g + 4);
        float4 v0 = *(const float4*)(b2 + g), v1 = *(const float4*)(b2 + g + 4);
        float sa = s1[c], sb = s2[c];
        union { __half2 h2[4]; uint4 q; } A, Bv;
        A.h2[0] = __floats2half2_rn(u0.x * sa, u0.y * sa);
        A.h2[1] = __floats2half2_rn(u0.z * sa, u0.w * sa);
        A.h2[2] = __floats2half2_rn(u1.x * sa, u1.y * sa);
        A.h2[3] = __floats2half2_rn(u1.z * sa, u1.w * sa);
        Bv.h2[0] = __floats2half2_rn(v0.x * sb, v0.y * sb);
        Bv.h2[1] = __floats2half2_rn(v0.z * sb, v0.w * sb);
        Bv.h2[2] = __floats2half2_rn(v1.x * sb, v1.y * sb);
        Bv.h2[3] = __floats2half2_rn(v1.z * sb, v1.w * sb);
        char* pA = xsh + X1OFF + c * 72 + (r8 << 1);
        char* pB = xsh + c * 72 + (r8 << 1);
        *(uint2*)pA       = make_uint2(A.q.x, A.q.y);
        *(uint2*)(pA + 8) = make_uint2(A.q.z, A.q.w);
        *(uint2*)pB       = make_uint2(Bv.q.x, Bv.q.y);
        *(uint2*)(pB + 8) = make_uint2(Bv.q.z, Bv.q.w);
    }
    if (tid < 8) *(uint2*)(xsh + ZOFF + tid * 8) = make_uint2(0, 0);  // zero channel j=512
    __syncthreads();

    int wv = tid >> 6;                     // 0..15
    int lane = tid & 63;
    int grp = lane >> 3;                   // group: d within octet
    int l = lane & 7;                      // rows 4l..4l+3
    uint32_t baseA = (uint32_t)(X1OFF + (l << 3));
    uint32_t baseB = (uint32_t)(l << 3);
    int dbase = gy * (CBP_D / NSPLIT) + wv * 128;   // wave owns 128 contiguous d's
    int rr = lane & 31, dq = lane >> 5, kk = rr & 3;
    int srcb = (dq << 5) + (rr >> 2);      // transpose source base lane

    // cross-octet pipeline: count + first uint4 of the upcoming octet
    int nmax_cur = __builtin_amdgcn_readfirstlane(cnt[dbase]);
    uint4 pp_cur = *(const uint4*)(pairs + (size_t)(dbase + grp) * NCAP);

    // lane stores row r_base + rr, quads at d = dbase + 16*oo + 8*K + 4*dq
    float* obase = out + (size_t)(r_base + rr) * CBP_D + dbase + (dq << 2);

    for (int oo = 0; oo < 8; ++oo) {
        float4 B0, B1;
        OCT(0, B0); OCT(1, B1);
        float* o_ = obase + (oo << 4);
        *(float4*)(o_)     = B0;
        *(float4*)(o_ + 8) = B1;
    }
}

// ================= launch =================

extern "C" void kernel_launch(void* const* d_in, const int* in_sizes, int n_in,
                              void* d_out, int out_size, void* d_ws, size_t ws_size,
                              hipStream_t stream) {
    const float* b1 = (const float*)d_in[0];
    const float* b2 = (const float*)d_in[1];
    const int*   h1 = (const int*)d_in[2];
    const float* s1 = (const float*)d_in[3];
    const int*   h2 = (const int*)d_in[4];
    const float* s2 = (const float*)d_in[5];
    float* out = (float*)d_out;

    int* cnt = (int*)d_ws;                            // 8192 (+8 pad)
    uint32_t* pairs = (uint32_t*)(cnt + 8192 + 8);    // 8192*NCAP u32 (~2.36 MB)

    pB_fill<<<128, 512, 0, stream>>>(h1, h2, cnt, pairs);

    dim3 g(CBP_W * 8 / ROWS, NSPLIT);     // (128, 4)
    k_main<<<g, NTHREADS, 0, stream>>>(b1, b2, s1, s2, cnt, pairs, out);
}

// Round 13
// 134.010 us; speedup vs baseline: 1.2049x; 1.1669x over previous
//
#include <hip/hip_runtime.h>
#include <hip/hip_fp16.h>
#include <stdint.h>

#define CBP_D 8192
#define CBP_C 512
#define CBP_W 512
#define ROWS 64          // rows staged per block; lane covers 8 rows (b128)
#define NTHREADS 1024    // 16 waves
#define NSPLIT 4         // 64 row-blocks x 4 = 256 blocks = 1/CU
#define NCAP 72          // fixed pair-list capacity per d (empirically sufficient)

// LDS layout (bytes): x2 ch 0..512 @128B (ch 512 = zeros), then x1 ch 0..511
#define X1OFF 65664      // 513*128
#define ZOFF  65536      // zero channel (j=512)
#define PADW  (512u << 17)   // pad pair word: j=512 (zero ch), i=0

// ================= precompute (single fused kernel) =================
// 128 blocks x 512 threads; block rebuilds h2 buckets in LDS, then builds
// pair lists for its 64 d's with 8 threads per d. OCTET-max padded (8
// consecutive d share a uniform count). Deterministic ordering throughout.
__global__ __launch_bounds__(512, 2)
void pB_fill(const int* __restrict__ h1, const int* __restrict__ h2,
             int* __restrict__ cnt, uint32_t* __restrict__ pairs) {
    __shared__ int sc[CBP_D];       // h2 histogram
    __shared__ int sb[CBP_D];       // bucket start offsets
    __shared__ int ssum[512];
    __shared__ short sbk[CBP_C];    // bucket-ordered j list
    __shared__ int sh1[CBP_C];
    __shared__ int sh2[CBP_C];
    __shared__ int pc[64][8];
    __shared__ int rawt[64];
    int tid = threadIdx.x;          // 512

    for (int k = tid; k < CBP_D; k += 512) sc[k] = 0;
    sh1[tid] = h1[tid];
    sh2[tid] = h2[tid];
    __syncthreads();
    atomicAdd(&sc[sh2[tid]], 1);
    __syncthreads();
    int base = tid * 16;
    int loc[16]; int s = 0;
#pragma unroll
    for (int k = 0; k < 16; ++k) { loc[k] = sc[base + k]; s += loc[k]; }
    ssum[tid] = s;
    __syncthreads();
    int acc = s;
    for (int off = 1; off < 512; off <<= 1) {
        int add = (tid >= off) ? ssum[tid - off] : 0;
        __syncthreads();
        acc += add; ssum[tid] = acc;
        __syncthreads();
    }
    int excl = acc - s;
#pragma unroll
    for (int k = 0; k < 16; ++k) { sb[base + k] = excl; excl += loc[k]; }
    __syncthreads();
    {
        int h = sh2[tid]; int r = 0;
        for (int j2 = 0; j2 < tid; ++j2) r += (sh2[j2] == h);
        sbk[sb[h] + r] = (short)tid;
    }
    __syncthreads();

    // ---- pair-list build: 8 threads per d, 64 d's per block ----
    int dl = tid >> 3, p = tid & 7;
    int d = blockIdx.x * 64 + dl;
    int i0 = p << 6;
    int cp = 0;
#pragma unroll 4
    for (int i = i0; i < i0 + 64; ++i) cp += sc[(d - sh1[i]) & (CBP_D - 1)];
    pc[dl][p] = cp;
    __syncthreads();
    int off = 0, tot = 0;
#pragma unroll
    for (int p2 = 0; p2 < 8; ++p2) { int v = pc[dl][p2]; off += (p2 < p) ? v : 0; tot += v; }
    uint32_t* pd = pairs + (size_t)d * NCAP;
    int pos = off;
    for (int i = i0; i < i0 + 64; ++i) {
        int t = (d - sh1[i]) & (CBP_D - 1);
        int n = sc[t];
        if (n) {
            int bo = sb[t];
            uint32_t iw = (uint32_t)(i << 7);
            for (int k = 0; k < n; ++k)
                pd[pos++] = iw | ((uint32_t)sbk[bo + k] << 17);
        }
    }
    if (p == 0) rawt[dl] = tot;
    __syncthreads();
    int q = dl & ~7;                // octet of 8 consecutive d
    int omax = 0;
#pragma unroll
    for (int z = 0; z < 8; ++z) omax = max(omax, rawt[q + z]);
    omax = (omax + 3) & ~3;
    for (int pos2 = tot + p; pos2 < omax; pos2 += 8) pd[pos2] = PADW;
    if (p == 0) cnt[d] = omax;
}

// ================= main =================

// Group grp (lane>>3) owns d = octb+grp; lane l (lane&7) covers rows 8l..8l+7
// via one ds_read_b128 per operand (128B aligned per group => conflict-free).
#define PROC(P) { \
    uint32_t p_ = (P); \
    uint32_t aB_ = (p_ & 0x1FF80u) + baseA; \
    uint32_t bB_ = ((p_ >> 10) & 0x1FF80u) + baseB; \
    uint4 ra_ = *(const uint4*)(xsh + aB_); \
    uint4 rb_ = *(const uint4*)(xsh + bB_); \
    a01 = __hfma2(*(const __half2*)&ra_.x, *(const __half2*)&rb_.x, a01); \
    a23 = __hfma2(*(const __half2*)&ra_.y, *(const __half2*)&rb_.y, a23); \
    a45 = __hfma2(*(const __half2*)&ra_.z, *(const __half2*)&rb_.z, a45); \
    a67 = __hfma2(*(const __half2*)&ra_.w, *(const __half2*)&rb_.w, a67); }

// One octet (8 consecutive d). After the 3-stage butterfly transpose, this
// lane holds row 8*(lane&7)+(lane>>3) for d = octb+0..7 -> DST0/DST1.
#define OCT(K, DST0, DST1) { \
    int oc_ = (oo << 1) + (K); \
    int octb_ = dbase + (oc_ << 3); \
    int nmax_ = nmax_cur; \
    uint4 cur_ = pp_cur; \
    int no_ = (oc_ + 1 < 16) ? oc_ + 1 : 15; \
    int nmax_n_ = __builtin_amdgcn_readfirstlane(cnt[dbase + (no_ << 3)]); \
    uint4 pp_n_ = *(const uint4*)(pairs + (size_t)(dbase + (no_ << 3) + grp) * NCAP); \
    const uint4* pl4_ = (const uint4*)(pairs + (size_t)(octb_ + grp) * NCAP); \
    float f0 = 0.f, f1 = 0.f, f2 = 0.f, f3 = 0.f; \
    float f4 = 0.f, f5 = 0.f, f6 = 0.f, f7 = 0.f; \
    int nb_ = nmax_ >> 2; \
    int t4_ = 0; \
    while (t4_ < nb_) { \
        __half2 a01 = __floats2half2_rn(0.f, 0.f); \
        __half2 a23 = a01, a45 = a01, a67 = a01; \
        int ce_ = (t4_ + 4 < nb_) ? t4_ + 4 : nb_; \
        for (; t4_ < ce_; ++t4_) { \
            uint4 c_ = cur_; \
            int nxt_ = (t4_ + 1 < nb_) ? t4_ + 1 : t4_; \
            cur_ = pl4_[nxt_]; \
            PROC(c_.x); PROC(c_.y); PROC(c_.z); PROC(c_.w); \
        } \
        float2 u_; \
        u_ = __half22float2(a01); f0 += u_.x; f1 += u_.y; \
        u_ = __half22float2(a23); f2 += u_.x; f3 += u_.y; \
        u_ = __half22float2(a45); f4 += u_.x; f5 += u_.y; \
        u_ = __half22float2(a67); f6 += u_.x; f7 += u_.y; \
    } \
    nmax_cur = nmax_n_; pp_cur = pp_n_; \
    /* stage 0: xor 8, g bit0 vs a bit0 */ \
    { float t0 = __shfl_xor(f1, 8, 64), t1 = __shfl_xor(f0, 8, 64); \
      float t2 = __shfl_xor(f3, 8, 64), t3 = __shfl_xor(f2, 8, 64); \
      float t4 = __shfl_xor(f5, 8, 64), t5 = __shfl_xor(f4, 8, 64); \
      float t6 = __shfl_xor(f7, 8, 64), t7 = __shfl_xor(f6, 8, 64); \
      f0 = h0 ? t0 : f0; f1 = h0 ? f1 : t1; f2 = h0 ? t2 : f2; f3 = h0 ? f3 : t3; \
      f4 = h0 ? t4 : f4; f5 = h0 ? f5 : t5; f6 = h0 ? t6 : f6; f7 = h0 ? f7 : t7; } \
    /* stage 1: xor 16, g bit1 vs a bit1 */ \
    { float t0 = __shfl_xor(f2, 16, 64), t1 = __shfl_xor(f3, 16, 64); \
      float t2 = __shfl_xor(f0, 16, 64), t3 = __shfl_xor(f1, 16, 64); \
      float t4 = __shfl_xor(f6, 16, 64), t5 = __shfl_xor(f7, 16, 64); \
      float t6 = __shfl_xor(f4, 16, 64), t7 = __shfl_xor(f5, 16, 64); \
      f0 = h1 ? t0 : f0; f1 = h1 ? t1 : f1; f2 = h1 ? f2 : t2; f3 = h1 ? f3 : t3; \
      f4 = h1 ? t4 : f4; f5 = h1 ? t5 : f5; f6 = h1 ? f6 : t6; f7 = h1 ? f7 : t7; } \
    /* stage 2: xor 32, g bit2 vs a bit2 */ \
    { float t0 = __shfl_xor(f4, 32, 64), t1 = __shfl_xor(f5, 32, 64); \
      float t2 = __shfl_xor(f6, 32, 64), t3 = __shfl_xor(f7, 32, 64); \
      float t4 = __shfl_xor(f0, 32, 64), t5 = __shfl_xor(f1, 32, 64); \
      float t6 = __shfl_xor(f2, 32, 64), t7 = __shfl_xor(f3, 32, 64); \
      f0 = h2 ? t0 : f0; f1 = h2 ? t1 : f1; f2 = h2 ? t2 : f2; f3 = h2 ? t3 : f3; \
      f4 = h2 ? f4 : t4; f5 = h2 ? f5 : t5; f6 = h2 ? f6 : t6; f7 = h2 ? f7 : t7; } \
    DST0 = make_float4(f0, f1, f2, f3); \
    DST1 = make_float4(f4, f5, f6, f7); }

__global__ __launch_bounds__(NTHREADS, 4)
void k_main(const float* __restrict__ b1, const float* __restrict__ b2,
            const float* __restrict__ s1, const float* __restrict__ s2,
            const int* __restrict__ cnt, const uint32_t* __restrict__ pairs,
            float* __restrict__ out) {
    __shared__ __align__(16) char xsh[131200];   // x2 (513 ch incl zero) + x1 (512)
    int bx = blockIdx.x;                   // 0..63 row-block
    int gy = blockIdx.y;                   // 0..3
    int r_base = bx * ROWS;
    int b = r_base >> 9;
    int w0 = r_base & (CBP_W - 1);
    int tid = threadIdx.x;

    // stage sign-folded f16, transposed [c][r] @128B stride; x2 at 0, x1 at X1OFF
    for (int u = tid; u < CBP_C * 8; u += NTHREADS) {
        int c = u >> 3;
        int r8 = (u & 7) << 3;
        size_t g = ((size_t)(b * CBP_C + c)) * CBP_W + w0 + r8;
        float4 u0 = *(const float4*)(b1 + g), u1 = *(const float4*)(b1 + g + 4);
        float4 v0 = *(const float4*)(b2 + g), v1 = *(const float4*)(b2 + g + 4);
        float sa = s1[c], sb = s2[c];
        union { __half2 h2[4]; uint4 q; } A, Bv;
        A.h2[0] = __floats2half2_rn(u0.x * sa, u0.y * sa);
        A.h2[1] = __floats2half2_rn(u0.z * sa, u0.w * sa);
        A.h2[2] = __floats2half2_rn(u1.x * sa, u1.y * sa);
        A.h2[3] = __floats2half2_rn(u1.z * sa, u1.w * sa);
        Bv.h2[0] = __floats2half2_rn(v0.x * sb, v0.y * sb);
        Bv.h2[1] = __floats2half2_rn(v0.z * sb, v0.w * sb);
        Bv.h2[2] = __floats2half2_rn(v1.x * sb, v1.y * sb);
        Bv.h2[3] = __floats2half2_rn(v1.z * sb, v1.w * sb);
        *(uint4*)(xsh + X1OFF + (c << 7) + (r8 << 1)) = A.q;
        *(uint4*)(xsh + (c << 7) + (r8 << 1)) = Bv.q;
    }
    if (tid < 8) *(uint4*)(xsh + ZOFF + tid * 16) = make_uint4(0, 0, 0, 0);
    __syncthreads();

    int wv = tid >> 6;                     // 0..15
    int lane = tid & 63;
    int grp = lane >> 3;                   // group: d within octet
    int l = lane & 7;                      // rows 8l..8l+7
    bool h0 = (grp & 1) != 0, h1 = (grp & 2) != 0, h2 = (grp & 4) != 0;
    uint32_t baseA = (uint32_t)(X1OFF + (l << 4));
    uint32_t baseB = (uint32_t)(l << 4);
    int dbase = gy * (CBP_D / NSPLIT) + wv * 128;   // wave owns 128 contiguous d's

    // cross-octet pipeline: count + first uint4 of the upcoming octet
    int nmax_cur = __builtin_amdgcn_readfirstlane(cnt[dbase]);
    uint4 pp_cur = *(const uint4*)(pairs + (size_t)(dbase + grp) * NCAP);

    // after butterfly, lane stores row 8*(lane&7) + (lane>>3); 16 d (64B) per burst
    int rrow = (l << 3) + grp;
    float* obase = out + (size_t)(r_base + rrow) * CBP_D + dbase;

    for (int oo = 0; oo < 8; ++oo) {
        float4 B0, B1, B2, B3;
        OCT(0, B0, B1); OCT(1, B2, B3);
        float* o_ = obase + (oo << 4);
        *(float4*)(o_)      = B0;
        *(float4*)(o_ + 4)  = B1;
        *(float4*)(o_ + 8)  = B2;
        *(float4*)(o_ + 12) = B3;
    }
}

// ================= launch =================

extern "C" void kernel_launch(void* const* d_in, const int* in_sizes, int n_in,
                              void* d_out, int out_size, void* d_ws, size_t ws_size,
                              hipStream_t stream) {
    const float* b1 = (const float*)d_in[0];
    const float* b2 = (const float*)d_in[1];
    const int*   h1 = (const int*)d_in[2];
    const float* s1 = (const float*)d_in[3];
    const int*   h2 = (const int*)d_in[4];
    const float* s2 = (const float*)d_in[5];
    float* out = (float*)d_out;

    int* cnt = (int*)d_ws;                            // 8192 (+8 pad)
    uint32_t* pairs = (uint32_t*)(cnt + 8192 + 8);    // 8192*NCAP u32 (~2.36 MB)

    pB_fill<<<128, 512, 0, stream>>>(h1, h2, cnt, pairs);

    dim3 g(CBP_W * 8 / ROWS, NSPLIT);     // (64, 4)
    k_main<<<g, NTHREADS, 0, stream>>>(b1, b2, s1, s2, cnt, pairs, out);
}